// Round 2
// 224.864 us; speedup vs baseline: 1.0854x; 1.0854x over previous
//
#include <hip/hip_runtime.h>
#include <hip/hip_bf16.h>

// TMDConv (PaiNN/TorchMD-style) two-pass message passing on MI355X.
// R13 == R12 resubmitted verbatim (R12 bench was an infra failure: container
// acquisition failed twice; no counters produced, kernel never measured).
// R12 changes vs R11 (R11 evidence: pass1 63us VALUBusy 67% MfmaUtil 2.4%
// HBM 29% -> VALU/latency bound, not roofline; rest = 181us hides 2x
// mlp_kernel at 625 waves TOTAL = <8% occupancy ceiling):
//  - mlp_kernel: 64-thread/1-wave blocks -> 512-thread/8-wave blocks.
//    Wave w owns feature-tile w: GEMM1 1 tile/wave, GEMM2 3 tiles/wave
//    (g=0..2 at fixed t=wave, preserving the fused 12B record write).
//    Same math order -> bitwise-identical output. 5000 waves (~19.5/CU).
//  - pass1/pass2: masking made data-driven. combo1/combo2 get a zeroed
//    dummy row N; out-of-range jv lanes point at it, so padded slots load
//    exact zeros and need NO cmp/cndmask/msk-mul in phase B. NaN hazards
//    removed by zero-padding Asn/Au (wave0 else-path) and Wl (epilogue
//    else-path zero records).

#define F_DIM   128
#define F3_DIM  384
#define L_DIM   20
#define CAP     64          // max in-degree bucket capacity
#define BATCH   16

typedef __attribute__((ext_vector_type(8))) short short8;
typedef __attribute__((ext_vector_type(4))) float f32x4;
typedef __attribute__((ext_vector_type(4))) unsigned short us4;

struct u3 { unsigned a, b, c; };   // 12B record (dwordx3)

__device__ __forceinline__ unsigned short f2bf(float f) {
  union { float f; unsigned u; } a; a.f = f;
  unsigned u = a.u;
  u = (u + 0x7FFFu + ((u >> 16) & 1u)) >> 16;   // RNE
  return (unsigned short)u;
}
__device__ __forceinline__ float bf2f(unsigned short u) {
  union { unsigned u; float f; } a; a.u = ((unsigned)u) << 16;
  return a.f;
}

// ---------------------------------------------------------------------------
// fused cast+fill kernel (+ zeroing of the dummy pad rows of combo1/combo2)
__global__ __launch_bounds__(256) void cast_fill_kernel(
    const float* __restrict__ ms1_w, unsigned short* __restrict__ w_ms1,
    const float* __restrict__ ms2_w, unsigned short* __restrict__ w_ms2,
    const float* __restrict__ us1_w, unsigned short* __restrict__ w_us1,
    const float* __restrict__ us2_w, unsigned short* __restrict__ w_us2,
    const float* __restrict__ s,     unsigned short* __restrict__ sbf,
    const float* __restrict__ v,     us4* __restrict__ v4,
    const float* __restrict__ mv_w,  unsigned short* __restrict__ mvwB,
    const int* __restrict__ src, const int* __restrict__ dst,
    int* __restrict__ cursor, int* __restrict__ jbuf,
    unsigned short* __restrict__ c1pad, unsigned short* __restrict__ c2pad,
    int nF, int E)
{
  int i = blockIdx.x * 256 + threadIdx.x;
  if (i < 16384) w_ms1[i] = f2bf(ms1_w[i]);
  if (i < 49152) w_ms2[i] = f2bf(ms2_w[i]);
  if (i < 16384) w_us1[i] = f2bf(us1_w[i]);
  if (i < 49152) w_us2[i] = f2bf(us2_w[i]);
  if (i < nF)    sbf[i] = f2bf(s[i]);
  if (i < nF) {
    const float* vp = v + (size_t)i * 3;
    us4 o; o.x = f2bf(vp[0]); o.y = f2bf(vp[1]); o.z = f2bf(vp[2]); o.w = 0;
    v4[i] = o;
  }
  if (i < 384 * 32) {
    int o = i >> 5, k = i & 31;
    float val = (k < 20) ? mv_w[o * 20 + k] * 0.6324555320336759f : 0.f;
    mvwB[i] = f2bf(val);
  }
  if (i < 768) {           // dummy node row: 128 records x 12B = 768 ushorts
    c1pad[i] = 0;
    c2pad[i] = 0;
  }
  if (i < E) {
    int d = dst[i];
    int p = atomicAdd(&cursor[d], 1);
    if (p < CAP) jbuf[d * CAP + p] = src[i];
  }
}

// ---------------------------------------------------------------------------
// Yc[n][f] (12B) = { (ssp(X@W1^T+b1)@W2^T+b2) triplet , Vin[n][f] triplet }
// 8 waves per block, 16 nodes per block; wave w owns feature-tile t = w.
__global__ __launch_bounds__(512) void mlp_kernel(
    const unsigned short* __restrict__ X,    // [n][128] bf16
    const unsigned short* __restrict__ W1,   // [128][128] bf16
    const float* __restrict__ B1,            // [128]
    const unsigned short* __restrict__ W2,   // [384][128] bf16
    const float* __restrict__ B2,            // [384]
    const us4* __restrict__ Vin,             // [n][128] bf16 triplet
    unsigned short* __restrict__ Yc)         // [n][128] 12B records
{
  __shared__ float HT[128 * 17];
  const int lane = threadIdx.x & 63;
  const int wave = threadIdx.x >> 6;         // 0..7 = feature tile
  const int c    = lane & 15;
  const int quad = lane >> 4;
  const int m0   = blockIdx.x * 16;

  // GEMM1: this wave's single output tile t = wave
  f32x4 acc = (f32x4){0.f, 0.f, 0.f, 0.f};
#pragma unroll
  for (int kk = 0; kk < 4; kk++) {
    short8 a = *(const short8*)(X + (size_t)(m0 + c) * 128 + kk * 32 + quad * 8);
    short8 b = *(const short8*)(W1 + (size_t)(wave * 16 + c) * 128 + kk * 32 + quad * 8);
    acc = __builtin_amdgcn_mfma_f32_16x16x32_bf16(a, b, acc, 0, 0, 0);
  }
  {
    int k = wave * 16 + c;
    float bias = B1[k];
#pragma unroll
    for (int r = 0; r < 4; r++) {
      float h = acc[r] + bias;
      float sp = (h > 15.f) ? h : log1pf(__expf(h));
      sp -= 0.69314718056f;
      HT[k * 17 + quad * 4 + r] = sp;
    }
  }
  __syncthreads();

  // GEMM2: 3 tiles (g=0..2) at t = wave, so the 12B record write stays fused
  f32x4 acc2[3];
#pragma unroll
  for (int g = 0; g < 3; g++) acc2[g] = (f32x4){0.f, 0.f, 0.f, 0.f};
#pragma unroll
  for (int kk = 0; kk < 4; kk++) {
    short8 afr;
#pragma unroll
    for (int j = 0; j < 8; j++) {
      float hv = HT[(kk * 32 + quad * 8 + j) * 17 + c];
      afr[j] = (short)f2bf(hv);
    }
#pragma unroll
    for (int g = 0; g < 3; g++) {
      short8 b = *(const short8*)(W2 + (size_t)(g * 128 + wave * 16 + c) * 128 + kk * 32 + quad * 8);
      acc2[g] = __builtin_amdgcn_mfma_f32_16x16x32_bf16(afr, b, acc2[g], 0, 0, 0);
    }
  }
  {
    int f = wave * 16 + c;                   // feature in [0,128)
    float b0 = B2[f], b1 = B2[128 + f], b2 = B2[256 + f];
#pragma unroll
    for (int r = 0; r < 4; r++) {
      int m = quad * 4 + r;
      us4 vv = Vin[(size_t)(m0 + m) * 128 + f];
      unsigned p0 = f2bf(acc2[0][r] + b0);
      unsigned p1 = f2bf(acc2[1][r] + b1);
      unsigned p2 = f2bf(acc2[2][r] + b2);
      u3 rec;
      rec.a = p0 | (p1 << 16);
      rec.b = p2 | ((unsigned)vv.x << 16);
      rec.c = (unsigned)vv.y | ((unsigned)vv.z << 16);
      *(u3*)(Yc + ((size_t)(m0 + m) * 128 + f) * 6) = rec;
    }
  }
}

// ---------------------------------------------------------------------------
// pass 1 (fused W-GEMM): block = 1 dst node, 4 waves = (half) x (parity).
// 16-edge batches; phase B is mask-free: padded slots read the zeroed dummy
// row (j = nNodes) and zero-padded Asn/Au/Wl, so contributions are exact 0.
__global__ __launch_bounds__(256, 4) void pass1_kernel(
    const float* __restrict__ x,       // [N,3]
    const unsigned short* __restrict__ combo1, // [N+1,128] 12B {phi012,v012}
    const float* __restrict__ v,       // [N,128,3] fp32 (epilogue add)
    const float* __restrict__ s,       // [N,128]
    const unsigned short* __restrict__ mvwB,  // [384][32] bf16 scale-folded
    const float* __restrict__ mv_b,           // [384]
    const int* __restrict__ jbuf,      // [N,CAP] src ids
    const int* __restrict__ deg,
    float* __restrict__ vnew, us4* __restrict__ vnew4,
    float* __restrict__ snew, unsigned short* __restrict__ snew_bf, int nNodes)
{
  __shared__ unsigned short Asn[BATCH * 32];  // 1 KB  A-tile (bf16 sn rows)
  __shared__ float4 Au[BATCH];                // 256 B {u0,u1,u2,invr}
  __shared__ us4 Wl[BATCH * 128];             // 16 KB per-batch weight triplets
  __shared__ float red[512];                  // 2 KB  cross-wave reduction

  const int tid  = threadIdx.x;
  const int wave = tid >> 6, lane = tid & 63;
  const int half = wave >> 1, split = wave & 1;
  const int i = blockIdx.x;
  const int f = lane + 64 * half;             // feature in [0,128)
  const int c = lane & 15, quad = lane >> 4;

  int cnt = deg[i]; if (cnt > CAP) cnt = CAP;
  const int base = i * CAP;

  // B-frags + bias for this wave's 6 tiles: {2w,2w+1,2w+8,2w+9,2w+16,2w+17}
  short8 bfr[6]; float bias[6];
#pragma unroll
  for (int p = 0; p < 3; p++)
#pragma unroll
    for (int h = 0; h < 2; h++) {
      int t = 2 * wave + h + 8 * p;
      bfr[p * 2 + h]  = *(const short8*)(mvwB + (size_t)(t * 16 + c) * 32 + quad * 8);
      bias[p * 2 + h] = mv_b[t * 16 + c];
    }

  const float xi0 = x[i * 3], xi1 = x[i * 3 + 1], xi2 = x[i * 3 + 2];
  int jv = (lane < cnt) ? jbuf[base + lane] : nNodes;   // dummy row for pads

  float accV0 = 0.f, accV1 = 0.f, accV2 = 0.f, accS = 0.f;

  for (int bs = 0; bs < cnt; bs += BATCH) {
    int bcnt = cnt - bs; if (bcnt > BATCH) bcnt = BATCH;
    __syncthreads();                           // previous batch fully consumed

    if (wave == 0) {
      // ALL 64 lanes execute the shfl (source lanes must be exec-active);
      // e = bs + (lane&15) <= 48+15 = 63, always a valid source lane.
      int t16 = lane & (BATCH - 1);
      int e = bs + t16;
      int j = __shfl(jv, e);
      if (lane < BATCH) {
        if (e < cnt) {
          float d0 = x[j * 3]     - xi0;
          float d1 = x[j * 3 + 1] - xi1;
          float d2 = x[j * 3 + 2] - xi2;
          float r = sqrtf(d0 * d0 + d1 * d1 + d2 * d2 + 1e-5f);
          float invr = 1.0f / r;
          Au[lane] = make_float4(d0 * invr, d1 * invr, d2 * invr, invr);
          float theta = r * 0.6283185307179586f;
          float s1, c1;
          __sincosf(theta, &s1, &c1);
          float c2 = 2.f * c1;
          float pm2 = s1, pm1 = c2 * s1;
          Asn[lane * 32 + 0] = f2bf(pm2);
          Asn[lane * 32 + 1] = f2bf(pm1);
#pragma unroll
          for (int l = 2; l < L_DIM; l++) {
            float cur = c2 * pm1 - pm2;
            Asn[lane * 32 + l] = f2bf(cur);
            pm2 = pm1; pm1 = cur;
          }
#pragma unroll
          for (int l = L_DIM; l < 32; l++) Asn[lane * 32 + l] = 0;
        } else {
          // pad slot: finite zeros so phase B needs no masking
          Au[lane] = make_float4(0.f, 0.f, 0.f, 0.f);
#pragma unroll
          for (int l = 0; l < 32; l++) Asn[lane * 32 + l] = 0;
        }
      }
    }
    __syncthreads();

    // single 16-row MFMA group
    {
      short8 a = *(const short8*)&Asn[c * 32 + quad * 8];
      f32x4 acc[6];
#pragma unroll
      for (int q = 0; q < 6; q++)
        acc[q] = __builtin_amdgcn_mfma_f32_16x16x32_bf16(
            a, bfr[q], (f32x4){0.f, 0.f, 0.f, 0.f}, 0, 0, 0);
#pragma unroll
      for (int r = 0; r < 4; r++) {
        int el = quad * 4 + r;
        if (el < bcnt) {
          float invr = Au[el].w;
#pragma unroll
          for (int h = 0; h < 2; h++) {
            float wp0 = fmaf(acc[h][r],     invr, bias[h]);
            float wp1 = fmaf(acc[2 + h][r], invr, bias[2 + h]);
            float wp2 = fmaf(acc[4 + h][r], invr, bias[4 + h]);
            float w0 = (wp0 < 5.f) ? 0.5f * (__cosf(wp0 * 0.6283185307179586f) + 1.f) : 0.f;
            float w1 = (wp1 < 5.f) ? 0.5f * (__cosf(wp1 * 0.6283185307179586f) + 1.f) : 0.f;
            float w2 = (wp2 < 5.f) ? 0.5f * (__cosf(wp2 * 0.6283185307179586f) + 1.f) : 0.f;
            us4 o; o.x = f2bf(w0); o.y = f2bf(w1); o.z = f2bf(w2); o.w = 0;
            Wl[el * 128 + wave * 32 + h * 16 + c] = o;
          }
        } else {
          // zero records so phase B pads multiply against exact zeros
          us4 z; z.x = 0; z.y = 0; z.z = 0; z.w = 0;
          Wl[el * 128 + wave * 32 + c]      = z;
          Wl[el * 128 + wave * 32 + 16 + c] = z;
        }
      }
    }
    __syncthreads();

    // phase B: mask-free. Pad slots: j = nNodes -> cb = 0 -> m0=m1=m2=0,
    // and Au/Wl pads are finite zeros, so every contribution is exactly 0.
    u3 cb[8];
#pragma unroll
    for (int k = 0; k < 8; k++) {
      int j = __shfl(jv, bs + split + 2 * k);
      cb[k] = *(const u3*)(combo1 + ((size_t)j * 128 + f) * 6);
    }
#pragma unroll
    for (int k = 0; k < 8; k++) {
      int el = split + 2 * k;
      float4 u = Au[el];
      us4 wv = Wl[el * 128 + f];
      float ph0 = bf2f((unsigned short)(cb[k].a & 0xffff));
      float ph1 = bf2f((unsigned short)(cb[k].a >> 16));
      float ph2 = bf2f((unsigned short)(cb[k].b & 0xffff));
      float vx  = bf2f((unsigned short)(cb[k].b >> 16));
      float vy  = bf2f((unsigned short)(cb[k].c & 0xffff));
      float vz  = bf2f((unsigned short)(cb[k].c >> 16));
      float m0 = ph0 * bf2f(wv.x);
      float m1 = ph1 * bf2f(wv.y);
      float m2 = ph2 * bf2f(wv.z);
      accV0 = fmaf(vx, m0, fmaf(m2, u.x, accV0));
      accV1 = fmaf(vy, m0, fmaf(m2, u.y, accV1));
      accV2 = fmaf(vz, m0, fmaf(m2, u.z, accV2));
      accS += m1;
    }
  }

  const int idx = half * 64 + lane;
  __syncthreads();
  if (split == 1) {
    red[idx * 4 + 0] = accV0; red[idx * 4 + 1] = accV1;
    red[idx * 4 + 2] = accV2; red[idx * 4 + 3] = accS;
  }
  __syncthreads();
  if (split == 0) {
    accV0 += red[idx * 4 + 0]; accV1 += red[idx * 4 + 1];
    accV2 += red[idx * 4 + 2]; accS  += red[idx * 4 + 3];
    size_t b3 = (size_t)i * 384 + f * 3;
    float n0 = v[b3] + accV0, n1 = v[b3 + 1] + accV1, n2 = v[b3 + 2] + accV2;
    vnew[b3] = n0; vnew[b3 + 1] = n1; vnew[b3 + 2] = n2;
    us4 o; o.x = f2bf(n0); o.y = f2bf(n1); o.z = f2bf(n2); o.w = 0;
    vnew4[(size_t)i * 128 + f] = o;
    size_t b1 = (size_t)i * 128 + f;
    float sv = s[b1] + accS;
    snew[b1] = sv;
    snew_bf[b1] = f2bf(sv);
  }
}

// ---------------------------------------------------------------------------
// pass 2: block = 1 dst node, 4 waves = (feature half) x (edge parity).
// Mask-free accumulate via zeroed dummy row (j = nNodes for pad lanes).
__global__ __launch_bounds__(256, 4) void pass2_kernel(
    const float* __restrict__ vnew,   // [N,128,3] fp32
    const float* __restrict__ snew,   // [N,128]
    const unsigned short* __restrict__ combo2, // [N+1,128] 12B {s2 012, vnew 012}
    const int* __restrict__ jbuf, const int* __restrict__ deg,
    float* __restrict__ vout, float* __restrict__ sout, int nNodes)
{
  __shared__ float red[1024];
  const int wave = threadIdx.x >> 6, lane = threadIdx.x & 63;
  const int half = wave >> 1, split = wave & 1;
  const int i = blockIdx.x;
  const int f = lane + 64 * half;

  int cnt = deg[i]; if (cnt > CAP) cnt = CAP;
  const int base = i * CAP;
  int jv = (lane < cnt) ? jbuf[base + lane] : nNodes;   // dummy row for pads

  float accU0 = 0.f, accU1 = 0.f, accU2 = 0.f;
  float accM0 = 0.f, accM1 = 0.f, accM2 = 0.f;

  for (int b0 = split; b0 < cnt; b0 += 16) {
    u3 cb[8];
#pragma unroll
    for (int k = 0; k < 8; k++) {
      int e = b0 + 2 * k;
      int ec = (e < 63) ? e : 63;              // lane 63 holds dummy when e>=cnt
      int j = __shfl(jv, ec);
      cb[k] = *(const u3*)(combo2 + ((size_t)j * 128 + f) * 6);
    }
#pragma unroll
    for (int k = 0; k < 8; k++) {
      accM0 += bf2f((unsigned short)(cb[k].a & 0xffff));
      accM1 += bf2f((unsigned short)(cb[k].a >> 16));
      accM2 += bf2f((unsigned short)(cb[k].b & 0xffff));
      accU0 += bf2f((unsigned short)(cb[k].b >> 16));
      accU1 += bf2f((unsigned short)(cb[k].c & 0xffff));
      accU2 += bf2f((unsigned short)(cb[k].c >> 16));
    }
  }

  const int idx = half * 64 + lane;
  if (split == 1) {
    red[idx * 8 + 0] = accU0; red[idx * 8 + 1] = accU1; red[idx * 8 + 2] = accU2;
    red[idx * 8 + 3] = accM0; red[idx * 8 + 4] = accM1; red[idx * 8 + 5] = accM2;
  }
  __syncthreads();
  if (split == 0) {
    accU0 += red[idx * 8 + 0]; accU1 += red[idx * 8 + 1]; accU2 += red[idx * 8 + 2];
    accM0 += red[idx * 8 + 3]; accM1 += red[idx * 8 + 4]; accM2 += red[idx * 8 + 5];

    float dinv = 1.0f / (float)(cnt > 0 ? cnt : 1);
    float uv0 = accU0 * dinv, uv1 = accU1 * dinv, uv2 = accU2 * dinv;
    float avv = accM0 * dinv, asv = accM1 * dinv, ass = accM2 * dinv;
    float q = uv0 * uv0 + uv1 * uv1 + uv2 * uv2;
    float ds2 = (q / (q + 1e-5f)) * asv + ass;
    size_t b3 = (size_t)i * 384 + f * 3;
    vout[b3]     = vnew[b3]     + uv0 * avv;
    vout[b3 + 1] = vnew[b3 + 1] + uv1 * avv;
    vout[b3 + 2] = vnew[b3 + 2] + uv2 * avv;
    size_t b1 = (size_t)i * 128 + f;
    sout[b1] = snew[b1] + ds2;
  }
}

// ---------------------------------------------------------------------------
extern "C" void kernel_launch(void* const* d_in, const int* in_sizes, int n_in,
                              void* d_out, int out_size, void* d_ws, size_t ws_size,
                              hipStream_t stream)
{
  const float* x     = (const float*)d_in[0];
  const float* v     = (const float*)d_in[1];
  const float* s     = (const float*)d_in[2];
  const float* ms1_w = (const float*)d_in[3];
  const float* ms1_b = (const float*)d_in[4];
  const float* ms2_w = (const float*)d_in[5];
  const float* ms2_b = (const float*)d_in[6];
  const float* mv_w  = (const float*)d_in[7];
  const float* mv_b  = (const float*)d_in[8];
  const float* us1_w = (const float*)d_in[9];
  const float* us1_b = (const float*)d_in[10];
  const float* us2_w = (const float*)d_in[11];
  const float* us2_b = (const float*)d_in[12];
  const int*   src   = (const int*)d_in[13];
  const int*   dst   = (const int*)d_in[14];

  const int N = in_sizes[0] / 3;        // 10000
  const int E = in_sizes[13];           // 100000

  char* p = (char*)d_ws;
  auto alloc = [&](size_t bytes) -> void* {
    void* r = (void*)p;
    p += (bytes + 255) & ~(size_t)255;
    return r;
  };
  unsigned short* sbf   = (unsigned short*)alloc((size_t)N * 128 * 2);
  unsigned short* snbf  = (unsigned short*)alloc((size_t)N * 128 * 2);
  unsigned short* w_ms1 = (unsigned short*)alloc(16384 * 2);
  unsigned short* w_ms2 = (unsigned short*)alloc(49152 * 2);
  unsigned short* w_us1 = (unsigned short*)alloc(16384 * 2);
  unsigned short* w_us2 = (unsigned short*)alloc(49152 * 2);
  unsigned short* mvwB  = (unsigned short*)alloc(384 * 32 * 2);
  us4*   v4     = (us4*)alloc((size_t)N * 128 * 8);
  us4*   vnew4  = (us4*)alloc((size_t)N * 128 * 8);
  unsigned short* combo1 = (unsigned short*)alloc((size_t)(N + 1) * 128 * 12);
  unsigned short* combo2 = (unsigned short*)alloc((size_t)(N + 1) * 128 * 12);
  float* vnew   = (float*)alloc((size_t)N * 384 * 4);
  float* snew   = (float*)alloc((size_t)N * 128 * 4);
  int* cursor   = (int*)alloc((size_t)N * 4);           // becomes deg after fill
  int* jbuf     = (int*)alloc((size_t)N * CAP * 4);

  hipMemsetAsync(cursor, 0, (size_t)N * 4, stream);

  cast_fill_kernel<<<(N * 128 + 255) / 256, 256, 0, stream>>>(
      ms1_w, w_ms1, ms2_w, w_ms2, us1_w, w_us1, us2_w, w_us2,
      s, sbf, v, v4, mv_w, mvwB, src, dst, cursor, jbuf,
      combo1 + (size_t)N * 768, combo2 + (size_t)N * 768, N * 128, E);

  // combo1 = {phi triplet, v triplet}
  mlp_kernel<<<N / 16, 512, 0, stream>>>(sbf, w_ms1, ms1_b, w_ms2, ms2_b,
                                         v4, combo1);

  pass1_kernel<<<N, 256, 0, stream>>>(x, combo1, v, s, mvwB, mv_b,
                                      jbuf, cursor, vnew, vnew4, snew, snbf, N);

  // combo2 = {s2 triplet, vnew triplet}
  mlp_kernel<<<N / 16, 512, 0, stream>>>(snbf, w_us1, us1_b, w_us2, us2_b,
                                         vnew4, combo2);

  float* vout = (float*)d_out;
  float* sout = vout + (size_t)N * 384;
  pass2_kernel<<<N, 256, 0, stream>>>(vnew, snew, combo2, jbuf, cursor,
                                      vout, sout, N);
}